// Round 14
// baseline (304.024 us; speedup 1.0000x reference)
//
#include <hip/hip_runtime.h>
#include <cstdint>
#include <cstddef>

typedef __bf16 bf16;
typedef __bf16 bf16x8 __attribute__((ext_vector_type(8)));
typedef __bf16 bf16x4 __attribute__((ext_vector_type(4)));
typedef float  f32x4  __attribute__((ext_vector_type(4)));

#define C_EPS 1e-5f
#define NC_ 64
#define NH_ 256
#define NW_ 256
#define HP_ (NH_*NW_)

// workspace layout (bytes)
#define OFF_XH   0ull                  // xh: NHWC bf16, 67108864
#define OFF_EDGE 67108864ull           // edge: NHWC bf16 half-res, 16777216
#define OFF_W1   83886080ull
#define OFF_W2   83959808ull
#define OFF_AFF  84033536ull

// swizzled LDS byte offset for [pixel p][granule g] bf16 tile (128 B/pixel),
// 16-B-granule XOR swizzle: pixel stride 128 B == 32 banks -> must swizzle.
__device__ __forceinline__ int lds_off(int p, int g) {
    return p * 128 + (((g) ^ (p & 7)) << 4);
}

// ---------------------------------------------------------------------------
// pack weights into MFMA B-frag order + BN affine fold (proven r1-r13)
__global__ void k_pack(const float* __restrict__ w1, const float* __restrict__ w2,
                       const float* __restrict__ b1, const float* __restrict__ g1,
                       const float* __restrict__ be1, const float* __restrict__ m1,
                       const float* __restrict__ v1,
                       const float* __restrict__ b2, const float* __restrict__ g2,
                       const float* __restrict__ be2, const float* __restrict__ m2,
                       const float* __restrict__ v2,
                       bf16* __restrict__ wp1, bf16* __restrict__ wp2,
                       float* __restrict__ aff)
{
    int idx = blockIdx.x * 256 + threadIdx.x;
    if (idx < 2 * 36864) {
        int conv = idx / 36864;
        int u = idx - conv * 36864;
        int j  = u & 7;
        int l  = (u >> 3) & 63;
        int nb = (u >> 9) & 3;
        int kb = (u >> 11) & 1;
        int t  = u >> 12;                  // 0..8
        int co = nb * 16 + (l & 15);
        int ci = kb * 32 + ((l >> 4) << 3) + j;
        const float* w = conv ? w2 : w1;
        float val = w[(co * 64 + ci) * 9 + t];
        (conv ? wp2 : wp1)[u] = (bf16)val;
    } else {
        int c = idx - 2 * 36864;
        if (c < 64) {
            float s = g1[c] / sqrtf(v1[c] + C_EPS);
            aff[c]      = s;
            aff[64 + c] = b1[c] * s + (be1[c] - m1[c] * s);
        } else if (c < 128) {
            int cc = c - 64;
            float s = g2[cc] / sqrtf(v2[cc] + C_EPS);
            aff[128 + cc] = s;
            aff[192 + cc] = b2[cc] * s + (be2[cc] - m2[cc] * s);
        }
    }
}

// ---------------------------------------------------------------------------
// prep v2: NCHW f32 -> NHWC bf16 (xh) + half-res Haar edge (NHWC bf16).
// One block per (b, half-res row Y, W-half): rows 2Y,2Y+1 x 128 px.
// LDS 32768 B (256 pp x 128 B) -> 4-5 blocks/CU (vs r13's 64 KB / 2 blocks).
// Staging r10-style: 4-plane gather -> ds_write_b64; 16 iterations.
__global__ __launch_bounds__(256, 2)
void k_prep(const float* __restrict__ x, bf16* __restrict__ xh,
            bf16* __restrict__ edge)
{
    __shared__ uint4 smem[2048];                 // 32768 B
    char* sr = reinterpret_cast<char*>(smem);
    const int t = threadIdx.x;
    const int bid = blockIdx.x;
    const int half = bid & 1;
    const int Y = (bid >> 1) & 127;
    const int b = bid >> 8;
    const int xoff = half * 128;
    const float* xb = x + (size_t)b * NC_ * HP_;

    // phase 1: gather 4 planes/item, pack bf16x4, LDS transpose store
    for (int i = 0; i < 16; ++i) {
        int item = i * 256 + t;                  // 4096 = 2 r * 16 ci4 * 128 px
        int px  = item & 127;
        int ci4 = (item >> 7) & 15;
        int r   = item >> 11;
        const float* s = xb + (size_t)(ci4 * 4) * HP_ + (2 * Y + r) * NW_ + xoff + px;
        bf16x4 pk = { (bf16)s[0], (bf16)s[HP_], (bf16)s[2 * HP_], (bf16)s[3 * HP_] };
        int pp = r * 128 + px;
        *reinterpret_cast<bf16x4*>(sr + lds_off(pp, ci4 >> 1) + ((ci4 & 1) << 3)) = pk;
    }
    __syncthreads();

    // phase 2a: write xh (NHWC), coalesced uint4
    bf16* xhb = xh + ((size_t)b * NH_ + 2 * Y) * NW_ * 64;
    for (int i = 0; i < 8; ++i) {
        int u = i * 256 + t;                     // 2048 = 256 pp * 8 g
        int pp = u >> 3, g = u & 7;
        uint4 v = *reinterpret_cast<const uint4*>(sr + lds_off(pp, g));
        int row = pp >> 7, px = pp & 127;
        *reinterpret_cast<uint4*>(xhb + ((size_t)(row * NW_ + xoff + px)) * 64 + g * 8) = v;
    }

    // phase 2b: edge row Y (this half's 64 px), e = (3a-b-c-d)/2
    bf16* eb = edge + ((size_t)b * 128 + Y) * 128 * 64;
    for (int i = 0; i < 2; ++i) {
        int u = i * 256 + t;                     // 512 = 64 ex * 8 g
        int exl = u >> 3, g = u & 7;
        bf16x8 a  = *reinterpret_cast<const bf16x8*>(sr + lds_off(2 * exl, g));
        bf16x8 bb = *reinterpret_cast<const bf16x8*>(sr + lds_off(2 * exl + 1, g));
        bf16x8 c  = *reinterpret_cast<const bf16x8*>(sr + lds_off(128 + 2 * exl, g));
        bf16x8 d  = *reinterpret_cast<const bf16x8*>(sr + lds_off(129 + 2 * exl, g));
        bf16x8 e;
        #pragma unroll
        for (int j = 0; j < 8; ++j)
            e[j] = (bf16)((3.f * (float)a[j] - (float)bb[j] - (float)c[j] - (float)d[j]) * 0.5f);
        *reinterpret_cast<bf16x8*>(eb + (size_t)(half * 64 + exl) * 64 + g * 8) = e;
    }
}

// ---------------------------------------------------------------------------
// Fused conv block, 384 threads (6 waves) — r12's correctness-proven partition
// + r13's lean uint4 staging. LDS 54272 (3-block capable; occupancy target is
// register-bound 12 waves/CU = 2 blocks):
//   sx  [0,51200)     x 20x20 halo; h 18x18 later occupies [0,41472)
//   seA [41472,51200) edge px 0..75  — staged AFTER conv1 (x-tail dead then)
//   seB [51200,54272) edge px 76..99 — staged pre-barrier (own bytes)
// (384,3) caps regs at 170: need ~100 VGPR + 64 AGPR (acc1[4][4]). r12's
// spill came from its heavy cvt staging (+~25 VGPR), removed here.
// Spill tripwire: WRITE_SIZE >> 131 MB.
__global__ __launch_bounds__(384, 3)
void k_fused(const float* __restrict__ x, const bf16* __restrict__ xh,
             const bf16* __restrict__ edge, const bf16* __restrict__ wp1,
             const bf16* __restrict__ wp2, const float* __restrict__ aff,
             const float* __restrict__ aprelu, float* __restrict__ out)
{
    __shared__ uint4 smem[3392];                 // 54272 B
    char* sx  = reinterpret_cast<char*>(smem);
    char* seA = reinterpret_cast<char*>(smem) + 41472;
    char* seB = reinterpret_cast<char*>(smem) + 51200;
    const int t = threadIdx.x;

    // XCD-bijective swizzle (2048 blocks, 8 XCDs)
    const int bid = blockIdx.x;
    const int logical = (bid & 7) * 256 + (bid >> 3);
    const int x0 = (logical & 15) * 16;
    const int y0 = ((logical >> 4) & 15) * 16;
    const int bb = logical >> 8;

    // ---- phase 1a: stage x 20x20 halo from xh (uint4 granule copies)
    const bf16* xhb = xh + (size_t)bb * NH_ * NW_ * 64;
    for (int i = 0; i < 9; ++i) {
        int u = i * 384 + t;                     // 3200 = 400 px * 8 g
        if (u < 3200) {
            int p = u >> 3, g = u & 7;
            int r = p / 20, c = p - r * 20;
            int yy = y0 - 2 + r, xx = x0 - 2 + c;
            uint4 v = {0u, 0u, 0u, 0u};
            if (yy >= 0 && yy < NH_ && xx >= 0 && xx < NW_)
                v = *reinterpret_cast<const uint4*>(xhb + ((size_t)(yy * NW_ + xx)) * 64 + g * 8);
            *reinterpret_cast<uint4*>(sx + lds_off(p, g)) = v;
        }
    }
    // ---- phase 1b: stage seB = edge px 76..99 (192 granules, clamped)
    const bf16* eb = edge + (size_t)bb * 128 * 128 * 64;
    if (t < 192) {
        int p = 76 + (t >> 3), g = t & 7;
        int ry = p / 10, rx = p - ry * 10;
        int ryg = (y0 >> 1) - 1 + ry; ryg = ryg < 0 ? 0 : (ryg > 127 ? 127 : ryg);
        int rxg = (x0 >> 1) - 1 + rx; rxg = rxg < 0 ? 0 : (rxg > 127 ? 127 : rxg);
        uint4 v = *reinterpret_cast<const uint4*>(eb + ((size_t)(ryg * 128 + rxg)) * 64 + g * 8);
        *reinterpret_cast<uint4*>(seB + lds_off(p - 76, g)) = v;
    }
    __syncthreads();

    const int w = t >> 6, l = t & 63;            // w in 0..5
    const int l15 = l & 15, lg = l >> 4;

    // ---- phase 2: conv1 MFMAs -> 4 fragments/wave (r12 partition, proven)
    f32x4 acc1[4][4];
    #pragma unroll
    for (int j = 0; j < 4; ++j)
        #pragma unroll
        for (int cb = 0; cb < 4; ++cb) acc1[j][cb] = f32x4{0.f, 0.f, 0.f, 0.f};

    int prj[4], pcj[4];
    #pragma unroll
    for (int j = 0; j < 4; ++j) {
        int g = w + 6 * j;
        int p = g * 16 + l15; if (p > 323) p = 323;   // addr-safe clamp
        prj[j] = p / 18; pcj[j] = p - prj[j] * 18;
    }

    const bf16x8* wv1 = reinterpret_cast<const bf16x8*>(wp1);
    #pragma unroll
    for (int ky = 0; ky < 3; ++ky)
    #pragma unroll
    for (int kx = 0; kx < 3; ++kx)
    #pragma unroll
    for (int kb = 0; kb < 2; ++kb) {
        const int tap = ky * 3 + kx;
        bf16x8 wf[4];
        #pragma unroll
        for (int cb = 0; cb < 4; ++cb)
            wf[cb] = wv1[(((tap * 2 + kb) * 4 + cb) << 6) + l];
        #pragma unroll
        for (int j = 0; j < 4; ++j) {
            if (w + 6 * j > 20) continue;        // wave-uniform guard
            bf16x8 xf = *reinterpret_cast<const bf16x8*>(
                sx + lds_off((prj[j] + ky) * 20 + pcj[j] + kx, kb * 4 + lg));
            #pragma unroll
            for (int cb = 0; cb < 4; ++cb)
                acc1[j][cb] = __builtin_amdgcn_mfma_f32_16x16x32_bf16(wf[cb], xf, acc1[j][cb], 0, 0, 0);
        }
    }
    __syncthreads();                             // all x-LDS reads complete

    // ---- phase 3 epoch: (a) h over x px 0..323 (zero outside image =
    // conv2 SAME padding); (b) seA = edge px 0..75 into dead x-tail
    // [41472,51200). Disjoint byte ranges; no reads of either this epoch.
    {
        const float apv = aprelu[0];
        #pragma unroll
        for (int j = 0; j < 4; ++j) {
            int g = w + 6 * j;
            if (g > 20) continue;
            int p = g * 16 + l15;
            if (p < 324) {
                const int hy = y0 - 1 + prj[j];
                const int hx = x0 - 1 + pcj[j];
                const bool valid = (hy >= 0) && (hy < NH_) && (hx >= 0) && (hx < NW_);
                #pragma unroll
                for (int cb = 0; cb < 4; ++cb) {
                    f32x4 al = *reinterpret_cast<const f32x4*>(aff + cb * 16 + lg * 4);
                    f32x4 be = *reinterpret_cast<const f32x4*>(aff + 64 + cb * 16 + lg * 4);
                    bf16x4 pk;
                    #pragma unroll
                    for (int r = 0; r < 4; ++r) {
                        float zv = acc1[j][cb][r] * al[r] + be[r];
                        float hv = zv > 0.f ? zv : apv * zv;
                        pk[r] = valid ? (bf16)hv : (bf16)0.f;
                    }
                    *reinterpret_cast<bf16x4*>(sx + lds_off(p, cb * 2 + (lg >> 1)) + ((lg & 1) << 3)) = pk;
                }
            }
        }
        #pragma unroll
        for (int i = 0; i < 2; ++i) {
            int u = i * 384 + t;                 // 608 = 76 px * 8 g
            if (u < 608) {
                int p = u >> 3, g = u & 7;
                int ry = p / 10, rx = p - ry * 10;
                int ryg = (y0 >> 1) - 1 + ry; ryg = ryg < 0 ? 0 : (ryg > 127 ? 127 : ryg);
                int rxg = (x0 >> 1) - 1 + rx; rxg = rxg < 0 ? 0 : (rxg > 127 ? 127 : rxg);
                uint4 v = *reinterpret_cast<const uint4*>(eb + ((size_t)(ryg * 128 + rxg)) * 64 + g * 8);
                *reinterpret_cast<uint4*>(seA + lds_off(p, g)) = v;
            }
        }
    }
    __syncthreads();                             // h + seA visible to all

    // ---- phase 4: conv2 MFMAs (M = pixels, N = co); rows w,w+6,w+12 (<16)
    f32x4 acc2[3][4];
    #pragma unroll
    for (int a = 0; a < 3; ++a)
        #pragma unroll
        for (int b = 0; b < 4; ++b) acc2[a][b] = f32x4{0.f, 0.f, 0.f, 0.f};

    const bf16x8* wv2 = reinterpret_cast<const bf16x8*>(wp2);
    #pragma unroll
    for (int ky = 0; ky < 3; ++ky)
    #pragma unroll
    for (int kx = 0; kx < 3; ++kx)
    #pragma unroll
    for (int kb = 0; kb < 2; ++kb) {
        const int tap = ky * 3 + kx;
        bf16x8 wf[4];
        #pragma unroll
        for (int cb = 0; cb < 4; ++cb)
            wf[cb] = wv2[(((tap * 2 + kb) * 4 + cb) << 6) + l];
        #pragma unroll
        for (int j = 0; j < 3; ++j) {
            const int row = w + 6 * j;
            if (row > 15) continue;              // wave-uniform guard
            int p = (row + ky) * 18 + (l15 + kx);
            bf16x8 xf = *reinterpret_cast<const bf16x8*>(sx + lds_off(p, kb * 4 + lg));
            #pragma unroll
            for (int cb = 0; cb < 4; ++cb)
                acc2[j][cb] = __builtin_amdgcn_mfma_f32_16x16x32_bf16(xf, wf[cb], acc2[j][cb], 0, 0, 0);
        }
    }

    // ---- phase 5: BN2 + x (global f32) + bilinear(seA/seB), f32x4 stores.
    // Out row r uses se tap rows (r+1)>>1,+1; weight 0.25/0.75 by parity
    // (r12-proven identity).
    #pragma unroll
    for (int cb = 0; cb < 4; ++cb) {
        const int co = cb * 16 + l15;
        const int cib2 = co >> 3;
        const int cio = (co & 7) << 1;
        const float al = aff[128 + co];
        const float bt = aff[192 + co];
        const float* xs0 = x + ((size_t)bb * NC_ + co) * HP_;
        #pragma unroll
        for (int j = 0; j < 3; ++j) {
            const int row = w + 6 * j;
            if (row > 15) continue;
            const int t0 = (row + 1) >> 1;
            float et[2][4];
            #pragma unroll
            for (int sr = 0; sr < 2; ++sr)
                #pragma unroll
                for (int c = 0; c < 4; ++c) {
                    int ep = (t0 + sr) * 10 + (2 * lg + c);
                    const char* sep = (ep < 76) ? (seA + lds_off(ep, cib2))
                                                : (seB + lds_off(ep - 76, cib2));
                    et[sr][c] = (float)*reinterpret_cast<const bf16*>(sep + cio);
                }
            const int Y = y0 + row;
            const int Xb = x0 + lg * 4;
            const float wyl = (row & 1) ? 0.75f : 0.25f;
            f32x4 xq = *reinterpret_cast<const f32x4*>(xs0 + Y * NW_ + Xb);
            f32x4 o;
            #pragma unroll
            for (int rr = 0; rr < 4; ++rr) {
                const int rx0 = (rr + 1) >> 1;            // {0,1,1,2}
                const float wxl = (rr & 1) ? 0.75f : 0.25f;
                float e0 = wxl * et[0][rx0] + (1.f - wxl) * et[0][rx0 + 1];
                float e1 = wxl * et[1][rx0] + (1.f - wxl) * et[1][rx0 + 1];
                float e  = wyl * e0 + (1.f - wyl) * e1;
                o[rr] = acc2[j][cb][rr] * al + bt + xq[rr] + e;
            }
            float* os = out + ((size_t)bb * NC_ + co) * HP_ + Y * NW_ + Xb;
            *reinterpret_cast<f32x4*>(os) = o;
        }
    }
}

// ---------------------------------------------------------------------------
extern "C" void kernel_launch(void* const* d_in, const int* in_sizes, int n_in,
                              void* d_out, int out_size, void* d_ws, size_t ws_size,
                              hipStream_t stream)
{
    const float* x   = (const float*)d_in[0];
    const float* w1  = (const float*)d_in[1];
    const float* b1  = (const float*)d_in[2];
    const float* g1  = (const float*)d_in[3];
    const float* be1 = (const float*)d_in[4];
    const float* m1  = (const float*)d_in[5];
    const float* v1  = (const float*)d_in[6];
    const float* ap  = (const float*)d_in[7];
    const float* w2  = (const float*)d_in[8];
    const float* b2  = (const float*)d_in[9];
    const float* g2  = (const float*)d_in[10];
    const float* be2 = (const float*)d_in[11];
    const float* m2  = (const float*)d_in[12];
    const float* v2  = (const float*)d_in[13];

    char* ws = (char*)d_ws;
    bf16*  xhb  = (bf16*)(ws + OFF_XH);
    bf16*  ebuf = (bf16*)(ws + OFF_EDGE);
    bf16*  wp1  = (bf16*)(ws + OFF_W1);
    bf16*  wp2  = (bf16*)(ws + OFF_W2);
    float* aff  = (float*)(ws + OFF_AFF);
    float* outp = (float*)d_out;

    k_pack<<<dim3(290), dim3(256), 0, stream>>>(w1, w2, b1, g1, be1, m1, v1,
                                                b2, g2, be2, m2, v2, wp1, wp2, aff);
    k_prep<<<dim3(2048), dim3(256), 0, stream>>>(x, xhb, ebuf);
    k_fused<<<dim3(2048), dim3(384), 0, stream>>>(x, xhb, ebuf, wp1, wp2, aff, ap, outp);
}

// Round 15
// 175.076 us; speedup vs baseline: 1.7365x; 1.7365x over previous
//
#include <hip/hip_runtime.h>
#include <cstdint>
#include <cstddef>

typedef __bf16 bf16;
typedef __bf16 bf16x8 __attribute__((ext_vector_type(8)));
typedef __bf16 bf16x4 __attribute__((ext_vector_type(4)));
typedef float  f32x4  __attribute__((ext_vector_type(4)));

#define C_EPS 1e-5f
#define NC_ 64
#define NH_ 256
#define NW_ 256
#define HP_ (NH_*NW_)

// workspace layout (bytes)
#define OFF_W1   0ull
#define OFF_W2   73728ull
#define OFF_AFF  147456ull

// swizzled LDS byte offset for [pixel p][granule g] bf16 tile (128 B/pixel),
// 16-B-granule XOR swizzle: pixel stride 128 B == 32 banks -> must swizzle.
// granule g holds ci 8g..8g+7 (staging stores ci4 at g=ci4>>1, +8B if odd).
__device__ __forceinline__ int lds_off(int p, int g) {
    return p * 128 + (((g) ^ (p & 7)) << 4);
}

// ---------------------------------------------------------------------------
// pack weights into MFMA B-frag order + BN affine fold (proven r1-r14)
__global__ void k_pack(const float* __restrict__ w1, const float* __restrict__ w2,
                       const float* __restrict__ b1, const float* __restrict__ g1,
                       const float* __restrict__ be1, const float* __restrict__ m1,
                       const float* __restrict__ v1,
                       const float* __restrict__ b2, const float* __restrict__ g2,
                       const float* __restrict__ be2, const float* __restrict__ m2,
                       const float* __restrict__ v2,
                       bf16* __restrict__ wp1, bf16* __restrict__ wp2,
                       float* __restrict__ aff)
{
    int idx = blockIdx.x * 256 + threadIdx.x;
    if (idx < 2 * 36864) {
        int conv = idx / 36864;
        int u = idx - conv * 36864;
        int j  = u & 7;
        int l  = (u >> 3) & 63;
        int nb = (u >> 9) & 3;
        int kb = (u >> 11) & 1;
        int t  = u >> 12;                  // 0..8
        int co = nb * 16 + (l & 15);
        int ci = kb * 32 + ((l >> 4) << 3) + j;
        const float* w = conv ? w2 : w1;
        float val = w[(co * 64 + ci) * 9 + t];
        (conv ? wp2 : wp1)[u] = (bf16)val;
    } else {
        int c = idx - 2 * 36864;
        if (c < 64) {
            float s = g1[c] / sqrtf(v1[c] + C_EPS);
            aff[c]      = s;
            aff[64 + c] = b1[c] * s + (be1[c] - m1[c] * s);
        } else if (c < 128) {
            int cc = c - 64;
            float s = g2[cc] / sqrtf(v2[cc] + C_EPS);
            aff[128 + cc] = s;
            aff[192 + cc] = b2[cc] * s + (be2[cc] - m2[cc] * s);
        }
    }
}

// ---------------------------------------------------------------------------
// Fully fused (r10 structure, un-aliased se, vectorized se phase):
//   sx [0, 51200) : x 20x20 halo; later h 18x18 occupies [0,41472)
//   se [51200, 64000) : 10x10 half-res edge taps
// stage x -> bar -> [se vectorized (reads sx, writes se) + conv1 MFMA]
// -> bar -> h over x (zero outside image = conv2 SAME padding) -> bar
// -> conv2 MFMA -> BN2 + x + bilinear(se) -> out.   3 barriers.
// Keep __launch_bounds__(256,2): every tighter cap spills (r6/r11/r12/r14).
// Register reality: ~116 VGPR + 96 AGPR (acc1) -> 2 waves/SIMD, so the
// 64000-B LDS (2 blocks/CU) costs nothing.
__global__ __launch_bounds__(256, 2)
void k_fused(const float* __restrict__ x, const bf16* __restrict__ wp1,
             const bf16* __restrict__ wp2, const float* __restrict__ aff,
             const float* __restrict__ aprelu, float* __restrict__ out)
{
    __shared__ uint4 smem[4000];                 // 64000 B
    char* sx = reinterpret_cast<char*>(smem);
    char* se = reinterpret_cast<char*>(smem) + 51200;
    const int t = threadIdx.x;

    // XCD-bijective swizzle (2048 blocks, 8 XCDs): each XCD owns one image
    const int bid = blockIdx.x;
    const int logical = (bid & 7) * 256 + (bid >> 3);
    const int x0 = (logical & 15) * 16;
    const int y0 = ((logical >> 4) & 15) * 16;
    const int bb = logical >> 8;
    const float* xb = x + (size_t)bb * NC_ * HP_;

    // ---- phase 1: stage x 20x20 halo (origin y0-2, x0-2) x 64 ci as bf16
    for (int i = 0; i < 25; ++i) {
        int item = i * 256 + t;                  // 6400 = 16 ci4 * 400 px
        int ci4 = item / 400;
        int p   = item - ci4 * 400;
        int r = p / 20, c = p - r * 20;
        int yy = y0 - 2 + r, xx = x0 - 2 + c;
        float v0 = 0.f, v1 = 0.f, v2 = 0.f, v3 = 0.f;
        if (yy >= 0 && yy < NH_ && xx >= 0 && xx < NW_) {
            const float* s = xb + (size_t)(ci4 * 4) * HP_ + yy * NW_ + xx;
            v0 = s[0]; v1 = s[HP_]; v2 = s[2 * HP_]; v3 = s[3 * HP_];
        }
        bf16x4 pk = { (bf16)v0, (bf16)v1, (bf16)v2, (bf16)v3 };
        *reinterpret_cast<bf16x4*>(sx + lds_off(p, ci4 >> 1) + ((ci4 & 1) << 3)) = pk;
    }
    __syncthreads();

    const int w = t >> 6, l = t & 63;
    const int l15 = l & 15, lg = l >> 4;

    // ---- phase 2a: se taps, VECTORIZED — 800 units = 100 px * 8 granules,
    // each: 4 x ds_read_b128 (a,b,c,d rows of the 2x2 Haar block) + 8-wide
    // f32 math + 1 b128 write. Replaces r10's 6400 scalar-read units.
    // Reads sx, writes se: disjoint regions, safe alongside conv1's reads.
    for (int i = 0; i < 4; ++i) {
        int u = i * 256 + t;
        if (u < 800) {
            int hp = u >> 3, g = u & 7;
            int ry = hp / 10, rx = hp - ry * 10;
            int ryg = (y0 >> 1) - 1 + ry; ryg = ryg < 0 ? 0 : (ryg > 127 ? 127 : ryg);
            int rxg = (x0 >> 1) - 1 + rx; rxg = rxg < 0 ? 0 : (rxg > 127 ? 127 : rxg);
            int pA = (2 * ryg - y0 + 2) * 20 + (2 * rxg - x0 + 2);
            bf16x8 a  = *reinterpret_cast<const bf16x8*>(sx + lds_off(pA,      g));
            bf16x8 b_ = *reinterpret_cast<const bf16x8*>(sx + lds_off(pA + 1,  g));
            bf16x8 c_ = *reinterpret_cast<const bf16x8*>(sx + lds_off(pA + 20, g));
            bf16x8 d_ = *reinterpret_cast<const bf16x8*>(sx + lds_off(pA + 21, g));
            bf16x8 e;
            #pragma unroll
            for (int j = 0; j < 8; ++j)
                e[j] = (bf16)((3.f * (float)a[j] - (float)b_[j] - (float)c_[j] - (float)d_[j]) * 0.5f);
            *reinterpret_cast<bf16x8*>(se + lds_off(hp, g)) = e;
        }
    }

    // ---- phase 2b: conv1 MFMAs -> 18x18 h in registers (r10 verbatim)
    f32x4 acc1[6][4];
    #pragma unroll
    for (int j = 0; j < 6; ++j)
        #pragma unroll
        for (int cb = 0; cb < 4; ++cb) acc1[j][cb] = f32x4{0.f, 0.f, 0.f, 0.f};

    int prj[6], pcj[6];
    #pragma unroll
    for (int j = 0; j < 6; ++j) {
        int g = w + 4 * j;
        int p = g * 16 + l15; if (p > 323) p = 323;   // addr-safe clamp
        prj[j] = p / 18; pcj[j] = p - prj[j] * 18;
    }

    const bf16x8* wv1 = reinterpret_cast<const bf16x8*>(wp1);
    #pragma unroll
    for (int ky = 0; ky < 3; ++ky)
    #pragma unroll
    for (int kx = 0; kx < 3; ++kx)
    #pragma unroll
    for (int kb = 0; kb < 2; ++kb) {
        const int tap = ky * 3 + kx;
        bf16x8 wf[4];
        #pragma unroll
        for (int cb = 0; cb < 4; ++cb)
            wf[cb] = wv1[(((tap * 2 + kb) * 4 + cb) << 6) + l];
        #pragma unroll
        for (int j = 0; j < 6; ++j) {
            if (w + 4 * j > 20) continue;        // wave-uniform guard
            bf16x8 xf = *reinterpret_cast<const bf16x8*>(
                sx + lds_off((prj[j] + ky) * 20 + pcj[j] + kx, kb * 4 + lg));
            #pragma unroll
            for (int cb = 0; cb < 4; ++cb)
                acc1[j][cb] = __builtin_amdgcn_mfma_f32_16x16x32_bf16(wf[cb], xf, acc1[j][cb], 0, 0, 0);
        }
    }
    __syncthreads();                             // x reads + se writes complete

    // ---- phase 3: BN1 + PReLU, h over x px 0..323 (bytes [0,41472)).
    // h pixels whose GLOBAL coords fall outside the image must be ZERO
    // (conv2's SAME padding pads h with zeros) — not conv1-of-padded-x.
    {
        const float apv = aprelu[0];
        #pragma unroll
        for (int j = 0; j < 6; ++j) {
            int g = w + 4 * j;
            if (g > 20) continue;
            int p = g * 16 + l15;
            if (p < 324) {
                const int hy = y0 - 1 + prj[j];
                const int hx = x0 - 1 + pcj[j];
                const bool valid = (hy >= 0) && (hy < NH_) && (hx >= 0) && (hx < NW_);
                #pragma unroll
                for (int cb = 0; cb < 4; ++cb) {
                    f32x4 al = *reinterpret_cast<const f32x4*>(aff + cb * 16 + lg * 4);
                    f32x4 be = *reinterpret_cast<const f32x4*>(aff + 64 + cb * 16 + lg * 4);
                    bf16x4 pk;
                    #pragma unroll
                    for (int r = 0; r < 4; ++r) {
                        float zv = acc1[j][cb][r] * al[r] + be[r];
                        float hv = zv > 0.f ? zv : apv * zv;
                        pk[r] = valid ? (bf16)hv : (bf16)0.f;
                    }
                    *reinterpret_cast<bf16x4*>(sx + lds_off(p, cb * 2 + (lg >> 1)) + ((lg & 1) << 3)) = pk;
                }
            }
        }
    }
    __syncthreads();                             // h tile visible to all

    // ---- phase 4: conv2 MFMAs (M = pixels, N = co) (r10 verbatim)
    f32x4 acc2[4][4];
    #pragma unroll
    for (int a = 0; a < 4; ++a)
        #pragma unroll
        for (int b = 0; b < 4; ++b) acc2[a][b] = f32x4{0.f, 0.f, 0.f, 0.f};

    const bf16x8* wv2 = reinterpret_cast<const bf16x8*>(wp2);
    #pragma unroll
    for (int ky = 0; ky < 3; ++ky)
    #pragma unroll
    for (int kx = 0; kx < 3; ++kx)
    #pragma unroll
    for (int kb = 0; kb < 2; ++kb) {
        const int tap = ky * 3 + kx;
        bf16x8 wf[4];
        #pragma unroll
        for (int cb = 0; cb < 4; ++cb)
            wf[cb] = wv2[(((tap * 2 + kb) * 4 + cb) << 6) + l];
        #pragma unroll
        for (int pr = 0; pr < 4; ++pr) {
            int p = (w * 4 + pr + ky) * 18 + (l15 + kx);
            bf16x8 xf = *reinterpret_cast<const bf16x8*>(sx + lds_off(p, kb * 4 + lg));
            #pragma unroll
            for (int cb = 0; cb < 4; ++cb)
                acc2[pr][cb] = __builtin_amdgcn_mfma_f32_16x16x32_bf16(xf, wf[cb], acc2[pr][cb], 0, 0, 0);
        }
    }

    // ---- phase 5: BN2 + x (global, L2-hot) + bilinear(se), f32x4 stores
    #pragma unroll
    for (int cb = 0; cb < 4; ++cb) {
        const int co = cb * 16 + l15;
        const int cib2 = co >> 3;
        const int cio = (co & 7) << 1;
        float et[4][4];
        #pragma unroll
        for (int r = 0; r < 4; ++r)
            #pragma unroll
            for (int c = 0; c < 4; ++c) {
                int ep = (2 * w + r) * 10 + (2 * lg + c);
                et[r][c] = (float)*reinterpret_cast<const bf16*>(se + lds_off(ep, cib2) + cio);
            }
        const float al = aff[128 + co];
        const float bt = aff[192 + co];
        const float* xs0 = x + ((size_t)bb * NC_ + co) * HP_;
        #pragma unroll
        for (int pr = 0; pr < 4; ++pr) {
            const int Y = y0 + w * 4 + pr;
            const int Xb = x0 + lg * 4;
            const int ry0 = (pr == 0) ? 0 : (pr == 3 ? 2 : 1);
            const float wyl = (pr & 1) ? 0.75f : 0.25f;
            f32x4 xq = *reinterpret_cast<const f32x4*>(xs0 + Y * NW_ + Xb);
            f32x4 o;
            #pragma unroll
            for (int rr = 0; rr < 4; ++rr) {
                const int rx0 = (rr == 0) ? 0 : (rr == 3 ? 2 : 1);
                const float wxl = (rr & 1) ? 0.75f : 0.25f;
                float e0 = wxl * et[ry0][rx0]     + (1.f - wxl) * et[ry0][rx0 + 1];
                float e1 = wxl * et[ry0 + 1][rx0] + (1.f - wxl) * et[ry0 + 1][rx0 + 1];
                float e  = wyl * e0 + (1.f - wyl) * e1;
                o[rr] = acc2[pr][cb][rr] * al + bt + xq[rr] + e;
            }
            float* os = out + ((size_t)bb * NC_ + co) * HP_ + Y * NW_ + Xb;
            *reinterpret_cast<f32x4*>(os) = o;
        }
    }
}

// ---------------------------------------------------------------------------
extern "C" void kernel_launch(void* const* d_in, const int* in_sizes, int n_in,
                              void* d_out, int out_size, void* d_ws, size_t ws_size,
                              hipStream_t stream)
{
    const float* x   = (const float*)d_in[0];
    const float* w1  = (const float*)d_in[1];
    const float* b1  = (const float*)d_in[2];
    const float* g1  = (const float*)d_in[3];
    const float* be1 = (const float*)d_in[4];
    const float* m1  = (const float*)d_in[5];
    const float* v1  = (const float*)d_in[6];
    const float* ap  = (const float*)d_in[7];
    const float* w2  = (const float*)d_in[8];
    const float* b2  = (const float*)d_in[9];
    const float* g2  = (const float*)d_in[10];
    const float* be2 = (const float*)d_in[11];
    const float* m2  = (const float*)d_in[12];
    const float* v2  = (const float*)d_in[13];

    char* ws = (char*)d_ws;
    bf16*  wp1  = (bf16*)(ws + OFF_W1);
    bf16*  wp2  = (bf16*)(ws + OFF_W2);
    float* aff  = (float*)(ws + OFF_AFF);
    float* outp = (float*)d_out;

    k_pack<<<dim3(290), dim3(256), 0, stream>>>(w1, w2, b1, g1, be1, m1, v1,
                                                b2, g2, be2, m2, v2, wp1, wp2, aff);
    k_fused<<<dim3(2048), dim3(256), 0, stream>>>(x, wp1, wp2, aff, ap, outp);
}

// Round 16
// 166.743 us; speedup vs baseline: 1.8233x; 1.0500x over previous
//
#include <hip/hip_runtime.h>
#include <cstdint>
#include <cstddef>

typedef __bf16 bf16;
typedef __bf16 bf16x8 __attribute__((ext_vector_type(8)));
typedef __bf16 bf16x4 __attribute__((ext_vector_type(4)));
typedef float  f32x4  __attribute__((ext_vector_type(4)));

#define C_EPS 1e-5f
#define NC_ 64
#define NH_ 256
#define NW_ 256
#define HP_ (NH_*NW_)

// workspace layout (bytes)
#define OFF_W1   0ull
#define OFF_W2   73728ull
#define OFF_AFF  147456ull

// swizzled LDS byte offset for [pixel p][granule g] bf16 tile (128 B/pixel),
// 16-B-granule XOR swizzle: pixel stride 128 B == 32 banks -> must swizzle.
// granule g holds ci 8g..8g+7 (staging stores ci4 at g=ci4>>1, +8B if odd).
__device__ __forceinline__ int lds_off(int p, int g) {
    return p * 128 + (((g) ^ (p & 7)) << 4);
}

// ---------------------------------------------------------------------------
// pack weights into MFMA B-frag order + BN affine fold (proven r1-r15)
__global__ void k_pack(const float* __restrict__ w1, const float* __restrict__ w2,
                       const float* __restrict__ b1, const float* __restrict__ g1,
                       const float* __restrict__ be1, const float* __restrict__ m1,
                       const float* __restrict__ v1,
                       const float* __restrict__ b2, const float* __restrict__ g2,
                       const float* __restrict__ be2, const float* __restrict__ m2,
                       const float* __restrict__ v2,
                       bf16* __restrict__ wp1, bf16* __restrict__ wp2,
                       float* __restrict__ aff)
{
    int idx = blockIdx.x * 256 + threadIdx.x;
    if (idx < 2 * 36864) {
        int conv = idx / 36864;
        int u = idx - conv * 36864;
        int j  = u & 7;
        int l  = (u >> 3) & 63;
        int nb = (u >> 9) & 3;
        int kb = (u >> 11) & 1;
        int t  = u >> 12;                  // 0..8
        int co = nb * 16 + (l & 15);
        int ci = kb * 32 + ((l >> 4) << 3) + j;
        const float* w = conv ? w2 : w1;
        float val = w[(co * 64 + ci) * 9 + t];
        (conv ? wp2 : wp1)[u] = (bf16)val;
    } else {
        int c = idx - 2 * 36864;
        if (c < 64) {
            float s = g1[c] / sqrtf(v1[c] + C_EPS);
            aff[c]      = s;
            aff[64 + c] = b1[c] * s + (be1[c] - m1[c] * s);
        } else if (c < 128) {
            int cc = c - 64;
            float s = g2[cc] / sqrtf(v2[cc] + C_EPS);
            aff[128 + cc] = s;
            aff[192 + cc] = b2[cc] * s + (be2[cc] - m2[cc] * s);
        }
    }
}

// ---------------------------------------------------------------------------
// Fully fused (r15 structure + LDS-transposed coalesced epilogue):
//   sx [0, 51200) : x 20x20 halo; then h 18x18 [0,41472); then acc [0,33792)
//   se [51200, 64000) : 10x10 half-res edge taps
// stage x -> bar -> [se vectorized + conv1 MFMA] -> bar -> h over x (zero
// outside image = conv2 SAME padding) -> bar -> conv2 MFMA -> bar ->
// acc2 as bf16 [co][yloc][X] over dead h region -> bar -> readback pass:
// 4-lane groups own (co,Y) rows -> BN2 + x + bilinear(se), fully COALESCED
// f32x4 x-loads and out-stores (was 64-way lane-scatter: co-strided).
// Keep __launch_bounds__(256,2): every tighter cap spills (r6/r11/r12/r14).
__global__ __launch_bounds__(256, 2)
void k_fused(const float* __restrict__ x, const bf16* __restrict__ wp1,
             const bf16* __restrict__ wp2, const float* __restrict__ aff,
             const float* __restrict__ aprelu, float* __restrict__ out)
{
    __shared__ uint4 smem[4000];                 // 64000 B
    char* sx = reinterpret_cast<char*>(smem);
    char* se = reinterpret_cast<char*>(smem) + 51200;
    const int t = threadIdx.x;

    // XCD-bijective swizzle (2048 blocks, 8 XCDs): each XCD owns one image
    const int bid = blockIdx.x;
    const int logical = (bid & 7) * 256 + (bid >> 3);
    const int x0 = (logical & 15) * 16;
    const int y0 = ((logical >> 4) & 15) * 16;
    const int bb = logical >> 8;
    const float* xb = x + (size_t)bb * NC_ * HP_;

    // ---- phase 1: stage x 20x20 halo (origin y0-2, x0-2) x 64 ci as bf16
    for (int i = 0; i < 25; ++i) {
        int item = i * 256 + t;                  // 6400 = 16 ci4 * 400 px
        int ci4 = item / 400;
        int p   = item - ci4 * 400;
        int r = p / 20, c = p - r * 20;
        int yy = y0 - 2 + r, xx = x0 - 2 + c;
        float v0 = 0.f, v1 = 0.f, v2 = 0.f, v3 = 0.f;
        if (yy >= 0 && yy < NH_ && xx >= 0 && xx < NW_) {
            const float* s = xb + (size_t)(ci4 * 4) * HP_ + yy * NW_ + xx;
            v0 = s[0]; v1 = s[HP_]; v2 = s[2 * HP_]; v3 = s[3 * HP_];
        }
        bf16x4 pk = { (bf16)v0, (bf16)v1, (bf16)v2, (bf16)v3 };
        *reinterpret_cast<bf16x4*>(sx + lds_off(p, ci4 >> 1) + ((ci4 & 1) << 3)) = pk;
    }
    __syncthreads();

    const int w = t >> 6, l = t & 63;
    const int l15 = l & 15, lg = l >> 4;

    // ---- phase 2a: se taps, vectorized (r15-proven): 800 units, b128 ops.
    // Reads sx, writes se: disjoint regions, safe alongside conv1's reads.
    for (int i = 0; i < 4; ++i) {
        int u = i * 256 + t;
        if (u < 800) {
            int hp = u >> 3, g = u & 7;
            int ry = hp / 10, rx = hp - ry * 10;
            int ryg = (y0 >> 1) - 1 + ry; ryg = ryg < 0 ? 0 : (ryg > 127 ? 127 : ryg);
            int rxg = (x0 >> 1) - 1 + rx; rxg = rxg < 0 ? 0 : (rxg > 127 ? 127 : rxg);
            int pA = (2 * ryg - y0 + 2) * 20 + (2 * rxg - x0 + 2);
            bf16x8 a  = *reinterpret_cast<const bf16x8*>(sx + lds_off(pA,      g));
            bf16x8 b_ = *reinterpret_cast<const bf16x8*>(sx + lds_off(pA + 1,  g));
            bf16x8 c_ = *reinterpret_cast<const bf16x8*>(sx + lds_off(pA + 20, g));
            bf16x8 d_ = *reinterpret_cast<const bf16x8*>(sx + lds_off(pA + 21, g));
            bf16x8 e;
            #pragma unroll
            for (int j = 0; j < 8; ++j)
                e[j] = (bf16)((3.f * (float)a[j] - (float)b_[j] - (float)c_[j] - (float)d_[j]) * 0.5f);
            *reinterpret_cast<bf16x8*>(se + lds_off(hp, g)) = e;
        }
    }

    // ---- phase 2b: conv1 MFMAs -> 18x18 h in registers (r10 verbatim)
    f32x4 acc1[6][4];
    #pragma unroll
    for (int j = 0; j < 6; ++j)
        #pragma unroll
        for (int cb = 0; cb < 4; ++cb) acc1[j][cb] = f32x4{0.f, 0.f, 0.f, 0.f};

    int prj[6], pcj[6];
    #pragma unroll
    for (int j = 0; j < 6; ++j) {
        int g = w + 4 * j;
        int p = g * 16 + l15; if (p > 323) p = 323;   // addr-safe clamp
        prj[j] = p / 18; pcj[j] = p - prj[j] * 18;
    }

    const bf16x8* wv1 = reinterpret_cast<const bf16x8*>(wp1);
    __builtin_amdgcn_s_setprio(1);
    #pragma unroll
    for (int ky = 0; ky < 3; ++ky)
    #pragma unroll
    for (int kx = 0; kx < 3; ++kx)
    #pragma unroll
    for (int kb = 0; kb < 2; ++kb) {
        const int tap = ky * 3 + kx;
        bf16x8 wf[4];
        #pragma unroll
        for (int cb = 0; cb < 4; ++cb)
            wf[cb] = wv1[(((tap * 2 + kb) * 4 + cb) << 6) + l];
        #pragma unroll
        for (int j = 0; j < 6; ++j) {
            if (w + 4 * j > 20) continue;        // wave-uniform guard
            bf16x8 xf = *reinterpret_cast<const bf16x8*>(
                sx + lds_off((prj[j] + ky) * 20 + pcj[j] + kx, kb * 4 + lg));
            #pragma unroll
            for (int cb = 0; cb < 4; ++cb)
                acc1[j][cb] = __builtin_amdgcn_mfma_f32_16x16x32_bf16(wf[cb], xf, acc1[j][cb], 0, 0, 0);
        }
    }
    __builtin_amdgcn_s_setprio(0);
    __syncthreads();                             // x reads + se writes complete

    // ---- phase 3: BN1 + PReLU, h over x px 0..323 (bytes [0,41472)).
    // h pixels whose GLOBAL coords fall outside the image must be ZERO
    // (conv2's SAME padding pads h with zeros) — not conv1-of-padded-x.
    {
        const float apv = aprelu[0];
        #pragma unroll
        for (int j = 0; j < 6; ++j) {
            int g = w + 4 * j;
            if (g > 20) continue;
            int p = g * 16 + l15;
            if (p < 324) {
                const int hy = y0 - 1 + prj[j];
                const int hx = x0 - 1 + pcj[j];
                const bool valid = (hy >= 0) && (hy < NH_) && (hx >= 0) && (hx < NW_);
                #pragma unroll
                for (int cb = 0; cb < 4; ++cb) {
                    f32x4 al = *reinterpret_cast<const f32x4*>(aff + cb * 16 + lg * 4);
                    f32x4 be = *reinterpret_cast<const f32x4*>(aff + 64 + cb * 16 + lg * 4);
                    bf16x4 pk;
                    #pragma unroll
                    for (int r = 0; r < 4; ++r) {
                        float zv = acc1[j][cb][r] * al[r] + be[r];
                        float hv = zv > 0.f ? zv : apv * zv;
                        pk[r] = valid ? (bf16)hv : (bf16)0.f;
                    }
                    *reinterpret_cast<bf16x4*>(sx + lds_off(p, cb * 2 + (lg >> 1)) + ((lg & 1) << 3)) = pk;
                }
            }
        }
    }
    __syncthreads();                             // h tile visible to all

    // ---- phase 4: conv2 MFMAs (M = pixels, N = co) (r10 verbatim)
    f32x4 acc2[4][4];
    #pragma unroll
    for (int a = 0; a < 4; ++a)
        #pragma unroll
        for (int b = 0; b < 4; ++b) acc2[a][b] = f32x4{0.f, 0.f, 0.f, 0.f};

    const bf16x8* wv2 = reinterpret_cast<const bf16x8*>(wp2);
    __builtin_amdgcn_s_setprio(1);
    #pragma unroll
    for (int ky = 0; ky < 3; ++ky)
    #pragma unroll
    for (int kx = 0; kx < 3; ++kx)
    #pragma unroll
    for (int kb = 0; kb < 2; ++kb) {
        const int tap = ky * 3 + kx;
        bf16x8 wf[4];
        #pragma unroll
        for (int cb = 0; cb < 4; ++cb)
            wf[cb] = wv2[(((tap * 2 + kb) * 4 + cb) << 6) + l];
        #pragma unroll
        for (int pr = 0; pr < 4; ++pr) {
            int p = (w * 4 + pr + ky) * 18 + (l15 + kx);
            bf16x8 xf = *reinterpret_cast<const bf16x8*>(sx + lds_off(p, kb * 4 + lg));
            #pragma unroll
            for (int cb = 0; cb < 4; ++cb)
                acc2[pr][cb] = __builtin_amdgcn_mfma_f32_16x16x32_bf16(xf, wf[cb], acc2[pr][cb], 0, 0, 0);
        }
    }
    __builtin_amdgcn_s_setprio(0);
    __syncthreads();                             // all h reads done -> h region dead

    // ---- phase 5a: stage acc2 as bf16 [co][yloc][X] over the dead h region.
    // co-stride 528 B (264 bf16, odd multiple of 16) -> b64 writes at the
    // 4-way bank floor. Thread (co=cb*16+l15, yloc=4w+pr, X=lg*4+rr).
    #pragma unroll
    for (int pr = 0; pr < 4; ++pr) {
        const int yloc = w * 4 + pr;
        #pragma unroll
        for (int cb = 0; cb < 4; ++cb) {
            const int co = cb * 16 + l15;
            bf16x4 pk;
            #pragma unroll
            for (int r = 0; r < 4; ++r) pk[r] = (bf16)acc2[pr][cb][r];
            *reinterpret_cast<bf16x4*>(sx + co * 528 + yloc * 32 + lg * 8) = pk;
        }
    }
    __syncthreads();

    // ---- phase 5b: readback. 4-lane groups own one (co, Y) row-quad ->
    // x-loads and out-stores are contiguous 64-B runs (16 tx/instr vs 64).
    // Same per-element math as r15 (row/col parity identities, r12-proven).
    {
        const float* xb2 = x + (size_t)bb * NC_ * HP_;
        float* ob = out + (size_t)bb * NC_ * HP_;
        const int Xq = t & 3;
        #pragma unroll
        for (int iter = 0; iter < 16; ++iter) {
            const int pi = iter * 64 + (t >> 2);
            const int co = pi & 63;
            const int yloc = pi >> 6;
            bf16x4 av = *reinterpret_cast<const bf16x4*>(sx + co * 528 + yloc * 32 + Xq * 8);
            const float al = aff[128 + co];
            const float bt = aff[192 + co];
            const int t0 = (yloc + 1) >> 1;
            const float wyl = (yloc & 1) ? 0.75f : 0.25f;
            const int cib2 = co >> 3, cio = (co & 7) << 1;
            float etc[2][4];
            #pragma unroll
            for (int sr = 0; sr < 2; ++sr)
                #pragma unroll
                for (int cc = 0; cc < 4; ++cc) {
                    int ep = (t0 + sr) * 10 + 2 * Xq + cc;
                    etc[sr][cc] = (float)*reinterpret_cast<const bf16*>(se + lds_off(ep, cib2) + cio);
                }
            const size_t goff = (size_t)co * HP_ + (y0 + yloc) * NW_ + x0 + Xq * 4;
            f32x4 xv = *reinterpret_cast<const f32x4*>(xb2 + goff);
            f32x4 o;
            #pragma unroll
            for (int rr = 0; rr < 4; ++rr) {
                const int rx0 = (rr + 1) >> 1;            // {0,1,1,2}
                const float wxl = (rr & 1) ? 0.75f : 0.25f;
                float e0 = wxl * etc[0][rx0] + (1.f - wxl) * etc[0][rx0 + 1];
                float e1 = wxl * etc[1][rx0] + (1.f - wxl) * etc[1][rx0 + 1];
                float e  = wyl * e0 + (1.f - wyl) * e1;
                o[rr] = (float)av[rr] * al + bt + xv[rr] + e;
            }
            *reinterpret_cast<f32x4*>(ob + goff) = o;
        }
    }
}

// ---------------------------------------------------------------------------
extern "C" void kernel_launch(void* const* d_in, const int* in_sizes, int n_in,
                              void* d_out, int out_size, void* d_ws, size_t ws_size,
                              hipStream_t stream)
{
    const float* x   = (const float*)d_in[0];
    const float* w1  = (const float*)d_in[1];
    const float* b1  = (const float*)d_in[2];
    const float* g1  = (const float*)d_in[3];
    const float* be1 = (const float*)d_in[4];
    const float* m1  = (const float*)d_in[5];
    const float* v1  = (const float*)d_in[6];
    const float* ap  = (const float*)d_in[7];
    const float* w2  = (const float*)d_in[8];
    const float* b2  = (const float*)d_in[9];
    const float* g2  = (const float*)d_in[10];
    const float* be2 = (const float*)d_in[11];
    const float* m2  = (const float*)d_in[12];
    const float* v2  = (const float*)d_in[13];

    char* ws = (char*)d_ws;
    bf16*  wp1  = (bf16*)(ws + OFF_W1);
    bf16*  wp2  = (bf16*)(ws + OFF_W2);
    float* aff  = (float*)(ws + OFF_AFF);
    float* outp = (float*)d_out;

    k_pack<<<dim3(290), dim3(256), 0, stream>>>(w1, w2, b1, g1, be1, m1, v1,
                                                b2, g2, be2, m2, v2, wp1, wp2, aff);
    k_fused<<<dim3(2048), dim3(256), 0, stream>>>(x, wp1, wp2, aff, ap, outp);
}

// Round 17
// 163.683 us; speedup vs baseline: 1.8574x; 1.0187x over previous
//
#include <hip/hip_runtime.h>
#include <cstdint>
#include <cstddef>

typedef __bf16 bf16;
typedef __bf16 bf16x8 __attribute__((ext_vector_type(8)));
typedef __bf16 bf16x4 __attribute__((ext_vector_type(4)));
typedef float  f32x4  __attribute__((ext_vector_type(4)));

#define C_EPS 1e-5f
#define NC_ 64
#define NH_ 256
#define NW_ 256
#define HP_ (NH_*NW_)

// workspace layout (bytes)
#define OFF_W1   0ull
#define OFF_W2   73728ull
#define OFF_AFF  147456ull

// acc staging stride (phase 5): 536 B -> 536/4 = 134 ≡ 6 (mod 32) banks,
// <=2-way aliasing (free); 528 gave ≡4 -> 4-way.
#define ACC_STRIDE 536

// swizzled LDS byte offset for [pixel p][granule g] bf16 tile (128 B/pixel),
// 16-B-granule XOR swizzle: pixel stride 128 B == 32 banks -> must swizzle.
// granule g holds ci 8g..8g+7 (staging stores ci4 at g=ci4>>1, +8B if odd).
__device__ __forceinline__ int lds_off(int p, int g) {
    return p * 128 + (((g) ^ (p & 7)) << 4);
}

// ---------------------------------------------------------------------------
// pack weights into MFMA B-frag order + BN affine fold (proven r1-r16)
__global__ void k_pack(const float* __restrict__ w1, const float* __restrict__ w2,
                       const float* __restrict__ b1, const float* __restrict__ g1,
                       const float* __restrict__ be1, const float* __restrict__ m1,
                       const float* __restrict__ v1,
                       const float* __restrict__ b2, const float* __restrict__ g2,
                       const float* __restrict__ be2, const float* __restrict__ m2,
                       const float* __restrict__ v2,
                       bf16* __restrict__ wp1, bf16* __restrict__ wp2,
                       float* __restrict__ aff)
{
    int idx = blockIdx.x * 256 + threadIdx.x;
    if (idx < 2 * 36864) {
        int conv = idx / 36864;
        int u = idx - conv * 36864;
        int j  = u & 7;
        int l  = (u >> 3) & 63;
        int nb = (u >> 9) & 3;
        int kb = (u >> 11) & 1;
        int t  = u >> 12;                  // 0..8
        int co = nb * 16 + (l & 15);
        int ci = kb * 32 + ((l >> 4) << 3) + j;
        const float* w = conv ? w2 : w1;
        float val = w[(co * 64 + ci) * 9 + t];
        (conv ? wp2 : wp1)[u] = (bf16)val;
    } else {
        int c = idx - 2 * 36864;
        if (c < 64) {
            float s = g1[c] / sqrtf(v1[c] + C_EPS);
            aff[c]      = s;
            aff[64 + c] = b1[c] * s + (be1[c] - m1[c] * s);
        } else if (c < 128) {
            int cc = c - 64;
            float s = g2[cc] / sqrtf(v2[cc] + C_EPS);
            aff[128 + cc] = s;
            aff[192 + cc] = b2[cc] * s + (be2[cc] - m2[cc] * s);
        }
    }
}

// ---------------------------------------------------------------------------
// Fully fused (r16 structure + float2 pair staging + 536 acc stride):
//   sx [0, 51200) : x 20x20 halo; then h 18x18 [0,41472); then acc [0,34304)
//   se [51200, 64000) : 10x10 half-res edge taps
// stage x (float2 pairs) -> bar -> [se vectorized + conv1 MFMA] -> bar ->
// h over x (zero outside image = conv2 SAME padding) -> bar -> conv2 MFMA
// -> bar -> acc2 bf16 [co][yloc][X] over dead h region -> bar -> readback:
// 4-lane groups own (co,Y) rows -> BN2 + x + bilinear(se), coalesced f32x4.
// Keep __launch_bounds__(256,2): every tighter cap spills (r6/r11/r12/r14).
__global__ __launch_bounds__(256, 2)
void k_fused(const float* __restrict__ x, const bf16* __restrict__ wp1,
             const bf16* __restrict__ wp2, const float* __restrict__ aff,
             const float* __restrict__ aprelu, float* __restrict__ out)
{
    __shared__ uint4 smem[4000];                 // 64000 B
    char* sx = reinterpret_cast<char*>(smem);
    char* se = reinterpret_cast<char*>(smem) + 51200;
    const int t = threadIdx.x;

    // XCD-bijective swizzle (2048 blocks, 8 XCDs): each XCD owns one image
    const int bid = blockIdx.x;
    const int logical = (bid & 7) * 256 + (bid >> 3);
    const int x0 = (logical & 15) * 16;
    const int y0 = ((logical >> 4) & 15) * 16;
    const int bb = logical >> 8;
    const float* xb = x + (size_t)bb * NC_ * HP_;

    // ---- phase 1: stage x 20x20 halo as PIXEL-PAIRS (float2 per plane).
    // xx is even and NW=256 -> a pair is all-in or all-out at boundaries,
    // so one guard covers both pixels. 3200 items = 16 ci4 * 200 pairs;
    // 50 x 8-B loads/thread (was 100 x 4-B). Values bit-identical to r16.
    for (int i = 0; i < 13; ++i) {
        int item = i * 256 + t;
        if (item < 3200) {
            int ci4 = item / 200;
            int pp  = item - ci4 * 200;          // pair 0..199
            int r   = pp / 10;
            int c2  = (pp - r * 10) * 2;         // 0,2,..,18
            int yy = y0 - 2 + r, xx = x0 - 2 + c2;
            float2 q0 = {0.f, 0.f}, q1 = {0.f, 0.f}, q2 = {0.f, 0.f}, q3 = {0.f, 0.f};
            if (yy >= 0 && yy < NH_ && xx >= 0 && xx < NW_) {
                const float* s = xb + (size_t)(ci4 * 4) * HP_ + yy * NW_ + xx;
                q0 = *reinterpret_cast<const float2*>(s);
                q1 = *reinterpret_cast<const float2*>(s + HP_);
                q2 = *reinterpret_cast<const float2*>(s + 2 * HP_);
                q3 = *reinterpret_cast<const float2*>(s + 3 * HP_);
            }
            int p = r * 20 + c2;
            int off = ((ci4 & 1) << 3);
            bf16x4 pkA = { (bf16)q0.x, (bf16)q1.x, (bf16)q2.x, (bf16)q3.x };
            bf16x4 pkB = { (bf16)q0.y, (bf16)q1.y, (bf16)q2.y, (bf16)q3.y };
            *reinterpret_cast<bf16x4*>(sx + lds_off(p,     ci4 >> 1) + off) = pkA;
            *reinterpret_cast<bf16x4*>(sx + lds_off(p + 1, ci4 >> 1) + off) = pkB;
        }
    }
    __syncthreads();

    const int w = t >> 6, l = t & 63;
    const int l15 = l & 15, lg = l >> 4;

    // ---- phase 2a: se taps, vectorized (r15-proven): 800 units, b128 ops.
    // Reads sx, writes se: disjoint regions, safe alongside conv1's reads.
    for (int i = 0; i < 4; ++i) {
        int u = i * 256 + t;
        if (u < 800) {
            int hp = u >> 3, g = u & 7;
            int ry = hp / 10, rx = hp - ry * 10;
            int ryg = (y0 >> 1) - 1 + ry; ryg = ryg < 0 ? 0 : (ryg > 127 ? 127 : ryg);
            int rxg = (x0 >> 1) - 1 + rx; rxg = rxg < 0 ? 0 : (rxg > 127 ? 127 : rxg);
            int pA = (2 * ryg - y0 + 2) * 20 + (2 * rxg - x0 + 2);
            bf16x8 a  = *reinterpret_cast<const bf16x8*>(sx + lds_off(pA,      g));
            bf16x8 b_ = *reinterpret_cast<const bf16x8*>(sx + lds_off(pA + 1,  g));
            bf16x8 c_ = *reinterpret_cast<const bf16x8*>(sx + lds_off(pA + 20, g));
            bf16x8 d_ = *reinterpret_cast<const bf16x8*>(sx + lds_off(pA + 21, g));
            bf16x8 e;
            #pragma unroll
            for (int j = 0; j < 8; ++j)
                e[j] = (bf16)((3.f * (float)a[j] - (float)b_[j] - (float)c_[j] - (float)d_[j]) * 0.5f);
            *reinterpret_cast<bf16x8*>(se + lds_off(hp, g)) = e;
        }
    }

    // ---- phase 2b: conv1 MFMAs -> 18x18 h in registers (r10 verbatim)
    f32x4 acc1[6][4];
    #pragma unroll
    for (int j = 0; j < 6; ++j)
        #pragma unroll
        for (int cb = 0; cb < 4; ++cb) acc1[j][cb] = f32x4{0.f, 0.f, 0.f, 0.f};

    int prj[6], pcj[6];
    #pragma unroll
    for (int j = 0; j < 6; ++j) {
        int g = w + 4 * j;
        int p = g * 16 + l15; if (p > 323) p = 323;   // addr-safe clamp
        prj[j] = p / 18; pcj[j] = p - prj[j] * 18;
    }

    const bf16x8* wv1 = reinterpret_cast<const bf16x8*>(wp1);
    __builtin_amdgcn_s_setprio(1);
    #pragma unroll
    for (int ky = 0; ky < 3; ++ky)
    #pragma unroll
    for (int kx = 0; kx < 3; ++kx)
    #pragma unroll
    for (int kb = 0; kb < 2; ++kb) {
        const int tap = ky * 3 + kx;
        bf16x8 wf[4];
        #pragma unroll
        for (int cb = 0; cb < 4; ++cb)
            wf[cb] = wv1[(((tap * 2 + kb) * 4 + cb) << 6) + l];
        #pragma unroll
        for (int j = 0; j < 6; ++j) {
            if (w + 4 * j > 20) continue;        // wave-uniform guard
            bf16x8 xf = *reinterpret_cast<const bf16x8*>(
                sx + lds_off((prj[j] + ky) * 20 + pcj[j] + kx, kb * 4 + lg));
            #pragma unroll
            for (int cb = 0; cb < 4; ++cb)
                acc1[j][cb] = __builtin_amdgcn_mfma_f32_16x16x32_bf16(wf[cb], xf, acc1[j][cb], 0, 0, 0);
        }
    }
    __builtin_amdgcn_s_setprio(0);
    __syncthreads();                             // x reads + se writes complete

    // ---- phase 3: BN1 + PReLU, h over x px 0..323 (bytes [0,41472)).
    // h pixels whose GLOBAL coords fall outside the image must be ZERO
    // (conv2's SAME padding pads h with zeros) — not conv1-of-padded-x.
    {
        const float apv = aprelu[0];
        #pragma unroll
        for (int j = 0; j < 6; ++j) {
            int g = w + 4 * j;
            if (g > 20) continue;
            int p = g * 16 + l15;
            if (p < 324) {
                const int hy = y0 - 1 + prj[j];
                const int hx = x0 - 1 + pcj[j];
                const bool valid = (hy >= 0) && (hy < NH_) && (hx >= 0) && (hx < NW_);
                #pragma unroll
                for (int cb = 0; cb < 4; ++cb) {
                    f32x4 al = *reinterpret_cast<const f32x4*>(aff + cb * 16 + lg * 4);
                    f32x4 be = *reinterpret_cast<const f32x4*>(aff + 64 + cb * 16 + lg * 4);
                    bf16x4 pk;
                    #pragma unroll
                    for (int r = 0; r < 4; ++r) {
                        float zv = acc1[j][cb][r] * al[r] + be[r];
                        float hv = zv > 0.f ? zv : apv * zv;
                        pk[r] = valid ? (bf16)hv : (bf16)0.f;
                    }
                    *reinterpret_cast<bf16x4*>(sx + lds_off(p, cb * 2 + (lg >> 1)) + ((lg & 1) << 3)) = pk;
                }
            }
        }
    }
    __syncthreads();                             // h tile visible to all

    // ---- phase 4: conv2 MFMAs (M = pixels, N = co) (r10 verbatim)
    f32x4 acc2[4][4];
    #pragma unroll
    for (int a = 0; a < 4; ++a)
        #pragma unroll
        for (int b = 0; b < 4; ++b) acc2[a][b] = f32x4{0.f, 0.f, 0.f, 0.f};

    const bf16x8* wv2 = reinterpret_cast<const bf16x8*>(wp2);
    __builtin_amdgcn_s_setprio(1);
    #pragma unroll
    for (int ky = 0; ky < 3; ++ky)
    #pragma unroll
    for (int kx = 0; kx < 3; ++kx)
    #pragma unroll
    for (int kb = 0; kb < 2; ++kb) {
        const int tap = ky * 3 + kx;
        bf16x8 wf[4];
        #pragma unroll
        for (int cb = 0; cb < 4; ++cb)
            wf[cb] = wv2[(((tap * 2 + kb) * 4 + cb) << 6) + l];
        #pragma unroll
        for (int pr = 0; pr < 4; ++pr) {
            int p = (w * 4 + pr + ky) * 18 + (l15 + kx);
            bf16x8 xf = *reinterpret_cast<const bf16x8*>(sx + lds_off(p, kb * 4 + lg));
            #pragma unroll
            for (int cb = 0; cb < 4; ++cb)
                acc2[pr][cb] = __builtin_amdgcn_mfma_f32_16x16x32_bf16(xf, wf[cb], acc2[pr][cb], 0, 0, 0);
        }
    }
    __builtin_amdgcn_s_setprio(0);
    __syncthreads();                             // all h reads done -> h region dead

    // ---- phase 5a: stage acc2 as bf16 [co][yloc][X] over the dead h region.
    // co-stride ACC_STRIDE=536 B -> <=2-way bank aliasing (free, m136).
    #pragma unroll
    for (int pr = 0; pr < 4; ++pr) {
        const int yloc = w * 4 + pr;
        #pragma unroll
        for (int cb = 0; cb < 4; ++cb) {
            const int co = cb * 16 + l15;
            bf16x4 pk;
            #pragma unroll
            for (int r = 0; r < 4; ++r) pk[r] = (bf16)acc2[pr][cb][r];
            *reinterpret_cast<bf16x4*>(sx + co * ACC_STRIDE + yloc * 32 + lg * 8) = pk;
        }
    }
    __syncthreads();

    // ---- phase 5b: readback. 4-lane groups own one (co, Y) row-quad ->
    // x-loads and out-stores are contiguous 64-B runs (16 tx/instr vs 64).
    // Same per-element math as r15 (row/col parity identities, r12-proven).
    {
        const float* xb2 = x + (size_t)bb * NC_ * HP_;
        float* ob = out + (size_t)bb * NC_ * HP_;
        const int Xq = t & 3;
        #pragma unroll
        for (int iter = 0; iter < 16; ++iter) {
            const int pi = iter * 64 + (t >> 2);
            const int co = pi & 63;
            const int yloc = pi >> 6;
            bf16x4 av = *reinterpret_cast<const bf16x4*>(sx + co * ACC_STRIDE + yloc * 32 + Xq * 8);
            const float al = aff[128 + co];
            const float bt = aff[192 + co];
            const int t0 = (yloc + 1) >> 1;
            const float wyl = (yloc & 1) ? 0.75f : 0.25f;
            const int cib2 = co >> 3, cio = (co & 7) << 1;
            float etc[2][4];
            #pragma unroll
            for (int sr = 0; sr < 2; ++sr)
                #pragma unroll
                for (int cc = 0; cc < 4; ++cc) {
                    int ep = (t0 + sr) * 10 + 2 * Xq + cc;
                    etc[sr][cc] = (float)*reinterpret_cast<const bf16*>(se + lds_off(ep, cib2) + cio);
                }
            const size_t goff = (size_t)co * HP_ + (y0 + yloc) * NW_ + x0 + Xq * 4;
            f32x4 xv = *reinterpret_cast<const f32x4*>(xb2 + goff);
            f32x4 o;
            #pragma unroll
            for (int rr = 0; rr < 4; ++rr) {
                const int rx0 = (rr + 1) >> 1;            // {0,1,1,2}
                const float wxl = (rr & 1) ? 0.75f : 0.25f;
                float e0 = wxl * etc[0][rx0] + (1.f - wxl) * etc[0][rx0 + 1];
                float e1 = wxl * etc[1][rx0] + (1.f - wxl) * etc[1][rx0 + 1];
                float e  = wyl * e0 + (1.f - wyl) * e1;
                o[rr] = (float)av[rr] * al + bt + xv[rr] + e;
            }
            *reinterpret_cast<f32x4*>(ob + goff) = o;
        }
    }
}

// ---------------------------------------------------------------------------
extern "C" void kernel_launch(void* const* d_in, const int* in_sizes, int n_in,
                              void* d_out, int out_size, void* d_ws, size_t ws_size,
                              hipStream_t stream)
{
    const float* x   = (const float*)d_in[0];
    const float* w1  = (const float*)d_in[1];
    const float* b1  = (const float*)d_in[2];
    const float* g1  = (const float*)d_in[3];
    const float* be1 = (const float*)d_in[4];
    const float* m1  = (const float*)d_in[5];
    const float* v1  = (const float*)d_in[6];
    const float* ap  = (const float*)d_in[7];
    const float* w2  = (const float*)d_in[8];
    const float* b2  = (const float*)d_in[9];
    const float* g2  = (const float*)d_in[10];
    const float* be2 = (const float*)d_in[11];
    const float* m2  = (const float*)d_in[12];
    const float* v2  = (const float*)d_in[13];

    char* ws = (char*)d_ws;
    bf16*  wp1  = (bf16*)(ws + OFF_W1);
    bf16*  wp2  = (bf16*)(ws + OFF_W2);
    float* aff  = (float*)(ws + OFF_AFF);
    float* outp = (float*)d_out;

    k_pack<<<dim3(290), dim3(256), 0, stream>>>(w1, w2, b1, g1, be1, m1, v1,
                                                b2, g2, be2, m2, v2, wp1, wp2, aff);
    k_fused<<<dim3(2048), dim3(256), 0, stream>>>(x, wp1, wp2, aff, ap, outp);
}